// Round 3
// baseline (172.166 us; speedup 1.0000x reference)
//
#include <hip/hip_runtime.h>
#include <hip/hip_bf16.h>

// Problem constants
#define Wd    96
#define Hd    96
#define HW    9216           // 96*96
#define Bn    4
#define Cn    64             // channels per section
#define C3    192            // 3*Cn
#define On    64             // out channels
#define NPIX  (Bn*HW)        // 36864
#define NFEAT (Bn*Cn*HW)     // 2359296 elements per output tensor
#define NWTB  (9*6*4*512)    // 110592 bf16 frag-linear deform weights
#define NWTB2 (18*2*64*8)    // 18432 bf16 frag-linear offset weights
#define NRB2  (Bn*(HW/16))   // 2304 repack blocks (16-px strips)

typedef __attribute__((ext_vector_type(8))) short s8v;    // 8 bf16
typedef __attribute__((ext_vector_type(4))) unsigned int u4v;
typedef __attribute__((ext_vector_type(4))) float f4v;    // MFMA accum / float4
typedef __hip_bfloat16 bf16;

__device__ __forceinline__ short f2bfs(float x) {
    return __builtin_bit_cast(short, __float2bfloat16(x));
}
__device__ __forceinline__ float blo(unsigned u) {
    return __builtin_bit_cast(float, u << 16);
}
__device__ __forceinline__ float bhi(unsigned u) {
    return __builtin_bit_cast(float, u & 0xffff0000u);
}
__device__ __forceinline__ unsigned packbf(float lo, float hi) {
    unsigned a = (unsigned)(unsigned short)f2bfs(lo);
    unsigned b = (unsigned)(unsigned short)f2bfs(hi);
    return a | (b << 16);
}

// ===========================================================================
// repack_wts: blocks [0, NRB2): NCHW ref/dist -> bf16 NHWC packed + fused
// diff. 16-px strips, all 4 float4 loads issued up-front per thread,
// bf16 pair-packing in-register, 6.5 KB u32 LDS transpose.
// blocks [NRB2, NRB2+1008): both weight repacks (frag-linear bf16).
// ===========================================================================
__global__ __launch_bounds__(128) void repack_wts_kernel(
        const float* __restrict__ ref,
        const float* __restrict__ dist,
        unsigned int* __restrict__ packed,    // [NPIX][96] bf16-pairs
        float* __restrict__ out_diff,
        const float* __restrict__ dw,
        const float* __restrict__ ow,
        bf16* __restrict__ wtb,
        bf16* __restrict__ wtb2) {
    __shared__ unsigned lds[96][17];          // 6528 B, stride 17 (odd) words

    int tid = threadIdx.x;

    if (blockIdx.x >= NRB2) {
        // ---- weight repack part ----
        int e = (int)(blockIdx.x - NRB2) * 128 + tid;
        if (e < NWTB) {
            int j = e & 7;
            int L = (e >> 3) & 63;
            int mt = (e >> 9) & 3;
            int rest = e >> 11;
            int kc = rest % 6;
            int tap = rest / 6;
            int o = mt * 16 + (L & 15);
            int c = kc * 32 + (L >> 4) * 8 + j;
            wtb[e] = __float2bfloat16(dw[((size_t)o * C3 + c) * 9 + tap]);
        } else if (e < NWTB + NWTB2) {
            int e2 = e - NWTB;
            int j = e2 & 7;
            int L = (e2 >> 3) & 63;
            int mt = (e2 >> 9) & 1;
            int kc2 = e2 >> 10;           // 0..17 = t*2+kc
            int v = mt * 16 + (L & 15);
            int k = kc2 * 32 + ((L >> 4) & 3) * 8 + j;
            int c = k & 63;
            int tap = k >> 6;
            float val = (v < 18) ? ow[((size_t)v * Cn + c) * 9 + tap] : 0.f;
            wtb2[e2] = __float2bfloat16(val);
        }
        return;
    }

    // ---- repack part: 16-px strip ----
    int blk = blockIdx.x;
    int b = blk / (HW / 16);
    int pb = (blk - b * (HW / 16)) * 16;
    int pxg = tid & 3;                        // 4 px-quads of 4
    int chp = tid >> 2;                       // channel pair 0..31

    size_t base0 = ((size_t)(b * Cn + 2 * chp)) * HW + pb + pxg * 4;
    size_t base1 = base0 + HW;

    // all 4 loads independent, issued before any dependent op
    f4v r0 = *(const f4v*)(ref + base0);
    f4v r1 = *(const f4v*)(ref + base1);
    f4v d0 = *(const f4v*)(dist + base0);
    f4v d1 = *(const f4v*)(dist + base1);

    f4v q0 = (r0 - d0) * (r0 - d0);
    f4v q1 = (r1 - d1) * (r1 - d1);
    *(f4v*)(out_diff + base0) = q0;
    *(f4v*)(out_diff + base1) = q1;

#pragma unroll
    for (int j = 0; j < 4; ++j) {
        int p = pxg * 4 + j;
        lds[chp][p]      = packbf(r0[j], r1[j]);
        lds[32 + chp][p] = packbf(d0[j], d1[j]);
        lds[64 + chp][p] = packbf(q0[j], q1[j]);
    }
    __syncthreads();

    unsigned* pko = packed + (size_t)(b * HW + pb) * 96;
#pragma unroll
    for (int k = 0; k < 12; ++k) {
        int i = tid + k * 128;
        int p = i / 96;
        int cp = i - p * 96;
        pko[p * 96 + cp] = lds[cp][p];        // bank (17cp+p)%32: conflict-free
    }
}

// ===========================================================================
// offset_mfma: M=v(32,18 used), N=16 px, K=576 split over 3 waves (3 taps
// each), LDS reduction. sched_barrier(0) pins the tap prefetch above the
// MFMA cluster so the compiler cannot sink the loads to their uses.
// ===========================================================================
__global__ __launch_bounds__(192) void offset_mfma(
        const bf16* __restrict__ packed,
        const bf16* __restrict__ wtb2,
        const float* __restrict__ ob,
        float* __restrict__ off) {
    __shared__ float red[2][64 * 9];          // 4608 B

    int tid = threadIdx.x;
    int L = tid & 63;
    int wv = tid / 64;                        // 0..2
    int px = L & 15;
    int lg = L >> 4;
    int blk = blockIdx.x;
    int region = (blk & 7) * 288 + (blk >> 3);        // 2304 blocks, XCD swizzle
    int p0 = region * 16;
    int b = p0 / HW;
    int pb = p0 - b * HW;
    int pid = pb + px;
    int x = pid % Wd, y = pid / Wd;
    int tbase = wv * 3;

    const s8v* Ap = (const s8v*)wtb2;
    const char* pkb = (const char*)packed + (size_t)b * HW * (C3 * 2);

    f4v acc0 = {0.f, 0.f, 0.f, 0.f};
    f4v acc1 = {0.f, 0.f, 0.f, 0.f};

    s8v rawo[2][2];
    short msk[2];

    // prologue: first tap of this wave
    {
        int t = tbase;
        int yy = y - 1 + t / 3, xx = x - 1 + t % 3;
        bool val = (unsigned)yy < (unsigned)Hd && (unsigned)xx < (unsigned)Wd;
        int oc = ((val ? yy : 0) * Wd + (val ? xx : 0)) * (C3 * 2);
        msk[0] = val ? (short)-1 : (short)0;
        rawo[0][0] = *(const s8v*)(pkb + oc + (0 * 4 + lg) * 16);
        rawo[0][1] = *(const s8v*)(pkb + oc + (1 * 4 + lg) * 16);
    }

#pragma unroll
    for (int tt = 0; tt < 3; ++tt) {
        int t = tbase + tt;
        if (tt < 2) {
            int tn = t + 1;
            int yy = y - 1 + tn / 3, xx = x - 1 + tn % 3;
            bool val = (unsigned)yy < (unsigned)Hd && (unsigned)xx < (unsigned)Wd;
            int oc = ((val ? yy : 0) * Wd + (val ? xx : 0)) * (C3 * 2);
            msk[(tt + 1) & 1] = val ? (short)-1 : (short)0;
            rawo[(tt + 1) & 1][0] = *(const s8v*)(pkb + oc + (0 * 4 + lg) * 16);
            rawo[(tt + 1) & 1][1] = *(const s8v*)(pkb + oc + (1 * 4 + lg) * 16);
        }
        __builtin_amdgcn_sched_barrier(0);    // pin prefetch above compute
        short m = msk[tt & 1];
#pragma unroll
        for (int kc = 0; kc < 2; ++kc) {
            s8v bfrag = rawo[tt & 1][kc] & m;
            s8v a0 = Ap[((t * 2 + kc) * 2 + 0) * 64 + L];
            s8v a1 = Ap[((t * 2 + kc) * 2 + 1) * 64 + L];
            acc0 = __builtin_amdgcn_mfma_f32_16x16x32_bf16(a0, bfrag, acc0, 0, 0, 0);
            acc1 = __builtin_amdgcn_mfma_f32_16x16x32_bf16(a1, bfrag, acc1, 0, 0, 0);
        }
    }

    // LDS reduction: waves 1,2 deposit partials; wave 0 sums + writes.
    if (wv != 0) {
        float* r = red[wv - 1] + L * 9;
#pragma unroll
        for (int i = 0; i < 4; ++i) r[i] = acc0[i];
#pragma unroll
        for (int i = 0; i < 4; ++i) r[4 + i] = acc1[i];
    }
    __syncthreads();
    if (wv == 0) {
        const float* r0 = red[0] + L * 9;
        const float* r1 = red[1] + L * 9;
        float* op = off + (size_t)(p0 + px) * 18;
#pragma unroll
        for (int r = 0; r < 4; ++r) {
            int v = lg * 4 + r;
            op[v] = acc0[r] + r0[r] + r1[r] + ob[v];
        }
        if (lg == 0) {
#pragma unroll
            for (int r = 0; r < 2; ++r)
                op[16 + r] = acc1[r] + r0[4 + r] + r1[4 + r] + ob[16 + r];
        }
    }
}

// ===========================================================================
// deform_mfma: M=o(64), N=16 px, K=1728 split over 3 waves (3 taps each),
// LDS reduction. The raw[2][12] software pipeline is pinned with
// sched_barrier(0): the 12 gather loads for half h+1 MUST issue before the
// bilinear+MFMA of half h (R2 showed the scheduler otherwise sinks them,
// VGPR_Count=52, pipeline serialized). launch_bounds(192,3) caps VGPR ~170.
// ===========================================================================
struct Ctx {
    int o00, o01, o10, o11;
    float W00, W01, W10, W11;
};

__device__ __forceinline__ Ctx mkctx(int t, int y, int x, float2 o2) {
    Ctx c;
    float py = (float)(y - 1 + t / 3) + o2.x;
    float pxs = (float)(x - 1 + t % 3) + o2.y;
    float fy = floorf(py), fx = floorf(pxs);
    int y0 = (int)fy, x0 = (int)fx;
    int y1 = y0 + 1, x1 = x0 + 1;
    float ay = py - fy, ax = pxs - fx;
    bool vy0 = (unsigned)y0 < (unsigned)Hd;
    bool vy1 = (unsigned)y1 < (unsigned)Hd;
    bool vx0 = (unsigned)x0 < (unsigned)Wd;
    bool vx1 = (unsigned)x1 < (unsigned)Wd;
    c.W00 = (vy0 && vx0) ? (1.f - ay) * (1.f - ax) : 0.f;
    c.W01 = (vy0 && vx1) ? (1.f - ay) * ax : 0.f;
    c.W10 = (vy1 && vx0) ? ay * (1.f - ax) : 0.f;
    c.W11 = (vy1 && vx1) ? ay * ax : 0.f;
    int y0c = min(max(y0, 0), Hd - 1), y1c = min(max(y1, 0), Hd - 1);
    int x0c = min(max(x0, 0), Wd - 1), x1c = min(max(x1, 0), Wd - 1);
    c.o00 = (y0c * Wd + x0c) * (C3 * 2);
    c.o01 = (y0c * Wd + x1c) * (C3 * 2);
    c.o10 = (y1c * Wd + x0c) * (C3 * 2);
    c.o11 = (y1c * Wd + x1c) * (C3 * 2);
    return c;
}

__global__ __launch_bounds__(192, 3) void deform_mfma(
        const bf16* __restrict__ packed,
        const float* __restrict__ off,     // [NPIX][18]
        const bf16* __restrict__ wtb,
        const float* __restrict__ db,
        float* __restrict__ out) {
    __shared__ float red[2][64 * 17];         // 8704 B

    int tid = threadIdx.x;
    int L = tid & 63;
    int wv = tid / 64;                        // 0..2
    int px = L & 15;
    int lg = L >> 4;
    int blk = blockIdx.x;
    int region = (blk & 7) * 288 + (blk >> 3);        // 2304 blocks, XCD swizzle
    int p0 = region * 16;
    int b = p0 / HW;
    int pb = p0 - b * HW;
    int pid = pb + px;
    int x = pid % Wd, y = pid / Wd;
    int tbase = wv * 3;

    const s8v* Ap = (const s8v*)wtb;
    const char* pkb = (const char*)packed + (size_t)b * HW * (C3 * 2);
    const float* offp = off + (size_t)(p0 + px) * 18;

    float2 o2a[3];
#pragma unroll
    for (int tt = 0; tt < 3; ++tt)
        o2a[tt] = *(const float2*)(offp + 2 * (tbase + tt));

    f4v acc[4];
    acc[0] = acc[1] = acc[2] = acc[3] = (f4v){0.f, 0.f, 0.f, 0.f};

    Ctx ctx[2];
    s8v raw[2][12];         // [buf][neighbor*3 + i]

    // prologue: first tap, half 0 (kc 0..2)
    ctx[0] = mkctx(tbase, y, x, o2a[0]);
#pragma unroll
    for (int i = 0; i < 3; ++i) {
        raw[0][0 * 3 + i] = *(const s8v*)(pkb + ctx[0].o00 + (i * 4 + lg) * 16);
        raw[0][1 * 3 + i] = *(const s8v*)(pkb + ctx[0].o01 + (i * 4 + lg) * 16);
        raw[0][2 * 3 + i] = *(const s8v*)(pkb + ctx[0].o10 + (i * 4 + lg) * 16);
        raw[0][3 * 3 + i] = *(const s8v*)(pkb + ctx[0].o11 + (i * 4 + lg) * 16);
    }

#pragma unroll
    for (int h = 0; h < 6; ++h) {             // 3 taps x 2 halves
        int tt = h >> 1;
        int t = tbase + tt;
        int kb = (h & 1) * 3;
        int cbuf = h & 1;
        if (h < 5) {
            int hn = h + 1;
            int ttn = hn >> 1;
            int kbn = (hn & 1) * 3;
            if ((hn & 1) == 0)
                ctx[ttn & 1] = mkctx(tbase + ttn, y, x, o2a[ttn]);
            const Ctx cn = ctx[ttn & 1];
#pragma unroll
            for (int i = 0; i < 3; ++i) {
                int kc = kbn + i;
                raw[hn & 1][0 * 3 + i] = *(const s8v*)(pkb + cn.o00 + (kc * 4 + lg) * 16);
                raw[hn & 1][1 * 3 + i] = *(const s8v*)(pkb + cn.o01 + (kc * 4 + lg) * 16);
                raw[hn & 1][2 * 3 + i] = *(const s8v*)(pkb + cn.o10 + (kc * 4 + lg) * 16);
                raw[hn & 1][3 * 3 + i] = *(const s8v*)(pkb + cn.o11 + (kc * 4 + lg) * 16);
            }
        }
        // Hard scheduling boundary: prefetch for h+1 stays issued above;
        // compute below waits only on buffer h (partial vmcnt).
        __builtin_amdgcn_sched_barrier(0);
        const Ctx cc = ctx[tt & 1];
#pragma unroll
        for (int i = 0; i < 3; ++i) {
            int kc = kb + i;
            u4v u00 = __builtin_bit_cast(u4v, raw[cbuf][0 * 3 + i]);
            u4v u01 = __builtin_bit_cast(u4v, raw[cbuf][1 * 3 + i]);
            u4v u10 = __builtin_bit_cast(u4v, raw[cbuf][2 * 3 + i]);
            u4v u11 = __builtin_bit_cast(u4v, raw[cbuf][3 * 3 + i]);
            u4v bu;
#pragma unroll
            for (int p = 0; p < 4; ++p) {
                float vlo = cc.W00 * blo(u00[p]) + cc.W01 * blo(u01[p])
                          + cc.W10 * blo(u10[p]) + cc.W11 * blo(u11[p]);
                float vhi = cc.W00 * bhi(u00[p]) + cc.W01 * bhi(u01[p])
                          + cc.W10 * bhi(u10[p]) + cc.W11 * bhi(u11[p]);
                bu[p] = packbf(vlo, vhi);
            }
            s8v bfrag = __builtin_bit_cast(s8v, bu);
#pragma unroll
            for (int mt = 0; mt < 4; ++mt) {
                s8v a = Ap[((t * 6 + kc) * 4 + mt) * 64 + L];
                acc[mt] = __builtin_amdgcn_mfma_f32_16x16x32_bf16(a, bfrag, acc[mt], 0, 0, 0);
            }
        }
    }

    // LDS reduction: waves 1,2 deposit 16 partials/lane; wave 0 sums+stores.
    if (wv != 0) {
        float* r = red[wv - 1] + L * 17;
#pragma unroll
        for (int mt = 0; mt < 4; ++mt)
#pragma unroll
            for (int q = 0; q < 4; ++q)
                r[mt * 4 + q] = acc[mt][q];
    }
    __syncthreads();
    if (wv == 0) {
        const float* r0 = red[0] + L * 17;
        const float* r1 = red[1] + L * 17;
#pragma unroll
        for (int mt = 0; mt < 4; ++mt) {
#pragma unroll
            for (int q = 0; q < 4; ++q) {
                int o = mt * 16 + lg * 4 + q;
                float v = acc[mt][q] + r0[mt * 4 + q] + r1[mt * 4 + q] + db[o];
                out[((size_t)(b * On + o)) * HW + pb + px] = fmaxf(v, 0.f);
            }
        }
    }
}

// ---------------------------------------------------------------------------
extern "C" void kernel_launch(void* const* d_in, const int* in_sizes, int n_in,
                              void* d_out, int out_size, void* d_ws, size_t ws_size,
                              hipStream_t stream) {
    const float* ref  = (const float*)d_in[0];
    const float* dist = (const float*)d_in[1];
    const float* ow   = (const float*)d_in[2];
    const float* ob   = (const float*)d_in[3];
    const float* dw   = (const float*)d_in[4];
    const float* db   = (const float*)d_in[5];

    float* out = (float*)d_out;               // [feat | diff], each NFEAT f32

    // ws: off [NPIX][18] f32 | wtb bf16 | wtb2 bf16 | packed bf16 [NPIX][192]
    float* ws_off = (float*)d_ws;
    bf16* ws_wtb  = (bf16*)((char*)d_ws + (size_t)NPIX * 18 * 4);
    bf16* ws_wtb2 = ws_wtb + NWTB;
    bf16* ws_pk   = ws_wtb2 + NWTB2;

    int wts_blocks = (NWTB + NWTB2 + 127) / 128;      // 1008
    repack_wts_kernel<<<NRB2 + wts_blocks, 128, 0, stream>>>(
        ref, dist, (unsigned int*)ws_pk, out + NFEAT, dw, ow, ws_wtb, ws_wtb2);
    offset_mfma<<<NPIX / 16, 192, 0, stream>>>(ws_pk, ws_wtb2, ob, ws_off);
    deform_mfma<<<NPIX / 16, 192, 0, stream>>>(ws_pk, ws_off, ws_wtb, db, out);
}

// Round 4
// 131.259 us; speedup vs baseline: 1.3116x; 1.3116x over previous
//
#include <hip/hip_runtime.h>
#include <hip/hip_bf16.h>

// Problem constants
#define Wd    96
#define Hd    96
#define HW    9216           // 96*96
#define Bn    4
#define Cn    64             // channels per section
#define C3    192            // 3*Cn
#define On    64             // out channels
#define NPIX  (Bn*HW)        // 36864
#define NFEAT (Bn*Cn*HW)     // 2359296 elements per output tensor
#define NWTB  (9*6*4*512)    // 110592 bf16 frag-linear deform weights
#define NWTB2 (18*2*64*8)    // 18432 bf16 frag-linear offset weights
#define NRB2  (Bn*(HW/16))   // 2304 repack blocks (16-px strips)

// Halo geometry for the fused kernel (16-px strip, one image row)
#define HR    5              // staged rows: yb-2 .. yb+2
#define HC    21             // staged cols: xb-3 .. xb+17
#define HPITCH 400           // bytes per staged pixel-row (384 + 16 pad)
#define NPR   (HR*HC)        // 105 staged pixel rows

typedef __attribute__((ext_vector_type(8))) short s8v;    // 8 bf16
typedef __attribute__((ext_vector_type(4))) unsigned int u4v;
typedef __attribute__((ext_vector_type(4))) float f4v;    // MFMA accum / float4
typedef __hip_bfloat16 bf16;

__device__ __forceinline__ short f2bfs(float x) {
    return __builtin_bit_cast(short, __float2bfloat16(x));
}
__device__ __forceinline__ float blo(unsigned u) {
    return __builtin_bit_cast(float, u << 16);
}
__device__ __forceinline__ float bhi(unsigned u) {
    return __builtin_bit_cast(float, u & 0xffff0000u);
}
__device__ __forceinline__ unsigned packbf(float lo, float hi) {
    unsigned a = (unsigned)(unsigned short)f2bfs(lo);
    unsigned b = (unsigned)(unsigned short)f2bfs(hi);
    return a | (b << 16);
}

// ===========================================================================
// repack_wts: UNCHANGED from R2 (so its top-5 appearance next round is
// attributable). blocks [0, NRB2): NCHW ref/dist -> bf16 NHWC packed +
// fused diff. blocks [NRB2, ...): both weight repacks.
// ===========================================================================
__global__ __launch_bounds__(128) void repack_wts_kernel(
        const float* __restrict__ ref,
        const float* __restrict__ dist,
        unsigned int* __restrict__ packed,    // [NPIX][96] bf16-pairs
        float* __restrict__ out_diff,
        const float* __restrict__ dw,
        const float* __restrict__ ow,
        bf16* __restrict__ wtb,
        bf16* __restrict__ wtb2) {
    __shared__ unsigned lds[96][17];          // 6528 B, stride 17 (odd) words

    int tid = threadIdx.x;

    if (blockIdx.x >= NRB2) {
        // ---- weight repack part ----
        int e = (int)(blockIdx.x - NRB2) * 128 + tid;
        if (e < NWTB) {
            int j = e & 7;
            int L = (e >> 3) & 63;
            int mt = (e >> 9) & 3;
            int rest = e >> 11;
            int kc = rest % 6;
            int tap = rest / 6;
            int o = mt * 16 + (L & 15);
            int c = kc * 32 + (L >> 4) * 8 + j;
            wtb[e] = __float2bfloat16(dw[((size_t)o * C3 + c) * 9 + tap]);
        } else if (e < NWTB + NWTB2) {
            int e2 = e - NWTB;
            int j = e2 & 7;
            int L = (e2 >> 3) & 63;
            int mt = (e2 >> 9) & 1;
            int kc2 = e2 >> 10;           // 0..17 = t*2+kc
            int v = mt * 16 + (L & 15);
            int k = kc2 * 32 + ((L >> 4) & 3) * 8 + j;
            int c = k & 63;
            int tap = k >> 6;
            float val = (v < 18) ? ow[((size_t)v * Cn + c) * 9 + tap] : 0.f;
            wtb2[e2] = __float2bfloat16(val);
        }
        return;
    }

    // ---- repack part: 16-px strip ----
    int blk = blockIdx.x;
    int b = blk / (HW / 16);
    int pb = (blk - b * (HW / 16)) * 16;
    int pxg = tid & 3;                        // 4 px-quads of 4
    int chp = tid >> 2;                       // channel pair 0..31

    size_t base0 = ((size_t)(b * Cn + 2 * chp)) * HW + pb + pxg * 4;
    size_t base1 = base0 + HW;

    f4v r0 = *(const f4v*)(ref + base0);
    f4v r1 = *(const f4v*)(ref + base1);
    f4v d0 = *(const f4v*)(dist + base0);
    f4v d1 = *(const f4v*)(dist + base1);

    f4v q0 = (r0 - d0) * (r0 - d0);
    f4v q1 = (r1 - d1) * (r1 - d1);
    *(f4v*)(out_diff + base0) = q0;
    *(f4v*)(out_diff + base1) = q1;

#pragma unroll
    for (int j = 0; j < 4; ++j) {
        int p = pxg * 4 + j;
        lds[chp][p]      = packbf(r0[j], r1[j]);
        lds[32 + chp][p] = packbf(d0[j], d1[j]);
        lds[64 + chp][p] = packbf(q0[j], q1[j]);
    }
    __syncthreads();

    unsigned* pko = packed + (size_t)(b * HW + pb) * 96;
#pragma unroll
    for (int k = 0; k < 12; ++k) {
        int i = tid + k * 128;
        int p = i / 96;
        int cp = i - p * 96;
        pko[p * 96 + cp] = lds[cp][p];        // bank (17cp+p)%32: conflict-free
    }
}

// ===========================================================================
// fused_mfma: stage 5x21 px halo of packed into LDS (coalesced, once),
// then Phase A (offset conv, pure-LDS reads) and Phase B (deform conv,
// LDS bilinear gathers, global fallback for out-of-halo offsets).
// 2304 blocks x 192 thr; LDS 51856 B -> 3 blocks/CU.
// ===========================================================================
struct Ctx {
    int o00, o01, o10, o11;      // global byte offsets (fallback path)
    int l00, l01, l10, l11;      // LDS byte offsets (fast path)
    float W00, W01, W10, W11;
    int inh;                     // all 4 corners inside staged halo
};

__device__ __forceinline__ Ctx mkctx(int t, int y, int x, int xb, float2 o2) {
    Ctx c;
    float py = (float)(y - 1 + t / 3) + o2.x;
    float pxs = (float)(x - 1 + t % 3) + o2.y;
    float fy = floorf(py), fx = floorf(pxs);
    int y0 = (int)fy, x0 = (int)fx;
    int y1 = y0 + 1, x1 = x0 + 1;
    float ay = py - fy, ax = pxs - fx;
    bool vy0 = (unsigned)y0 < (unsigned)Hd;
    bool vy1 = (unsigned)y1 < (unsigned)Hd;
    bool vx0 = (unsigned)x0 < (unsigned)Wd;
    bool vx1 = (unsigned)x1 < (unsigned)Wd;
    c.W00 = (vy0 && vx0) ? (1.f - ay) * (1.f - ax) : 0.f;
    c.W01 = (vy0 && vx1) ? (1.f - ay) * ax : 0.f;
    c.W10 = (vy1 && vx0) ? ay * (1.f - ax) : 0.f;
    c.W11 = (vy1 && vx1) ? ay * ax : 0.f;
    int y0c = min(max(y0, 0), Hd - 1), y1c = min(max(y1, 0), Hd - 1);
    int x0c = min(max(x0, 0), Wd - 1), x1c = min(max(x1, 0), Wd - 1);
    c.o00 = (y0c * Wd + x0c) * (C3 * 2);
    c.o01 = (y0c * Wd + x1c) * (C3 * 2);
    c.o10 = (y1c * Wd + x0c) * (C3 * 2);
    c.o11 = (y1c * Wd + x1c) * (C3 * 2);
    // LDS halo coordinates (valid content iff index in range: staged row at
    // iy is image row clamp(y-2+iy), so in-range index == row y0c exactly)
    int iy0 = y0c - y + 2, iy1 = y1c - y + 2;
    int ix0 = x0c - xb + 3, ix1 = x1c - xb + 3;
    c.inh = ((unsigned)iy0 < (unsigned)HR) & ((unsigned)iy1 < (unsigned)HR) &
            ((unsigned)ix0 < (unsigned)HC) & ((unsigned)ix1 < (unsigned)HC);
    c.l00 = (iy0 * HC + ix0) * HPITCH;
    c.l01 = (iy0 * HC + ix1) * HPITCH;
    c.l10 = (iy1 * HC + ix0) * HPITCH;
    c.l11 = (iy1 * HC + ix1) * HPITCH;
    return c;
}

__device__ __forceinline__ void bilin_mfma(const s8v* rw, const Ctx& cc,
        const s8v* __restrict__ Ap, int t, int kb, int L, f4v* acc) {
#pragma unroll
    for (int i = 0; i < 3; ++i) {
        int kc = kb + i;
        u4v u00 = __builtin_bit_cast(u4v, rw[0 * 3 + i]);
        u4v u01 = __builtin_bit_cast(u4v, rw[1 * 3 + i]);
        u4v u10 = __builtin_bit_cast(u4v, rw[2 * 3 + i]);
        u4v u11 = __builtin_bit_cast(u4v, rw[3 * 3 + i]);
        u4v bu;
#pragma unroll
        for (int p = 0; p < 4; ++p) {
            float vlo = cc.W00 * blo(u00[p]) + cc.W01 * blo(u01[p])
                      + cc.W10 * blo(u10[p]) + cc.W11 * blo(u11[p]);
            float vhi = cc.W00 * bhi(u00[p]) + cc.W01 * bhi(u01[p])
                      + cc.W10 * bhi(u10[p]) + cc.W11 * bhi(u11[p]);
            bu[p] = packbf(vlo, vhi);
        }
        s8v bfrag = __builtin_bit_cast(s8v, bu);
#pragma unroll
        for (int mt = 0; mt < 4; ++mt) {
            s8v a = Ap[((t * 6 + kc) * 4 + mt) * 64 + L];
            acc[mt] = __builtin_amdgcn_mfma_f32_16x16x32_bf16(a, bfrag, acc[mt], 0, 0, 0);
        }
    }
}

__global__ __launch_bounds__(192) void fused_mfma(
        const bf16* __restrict__ packed,
        const bf16* __restrict__ wtb2,
        const float* __restrict__ ob,
        const bf16* __restrict__ wtb,
        const float* __restrict__ db,
        float* __restrict__ out) {
    __shared__ f4v halo[NPR * (HPITCH / 16)];   // 42000 B
    __shared__ float red[2][64 * 17];           // 8704 B (shared by both phases)
    __shared__ float off_lds[16][18];           // 1152 B

    int tid = threadIdx.x;
    int L = tid & 63;
    int wv = tid / 64;                        // 0..2
    int px = L & 15;
    int lg = L >> 4;
    int blk = blockIdx.x;
    int region = (blk & 7) * 288 + (blk >> 3);        // 2304 blocks, XCD swizzle
    int p0 = region * 16;
    int b = p0 / HW;
    int pb = p0 - b * HW;
    int yb = pb / Wd;
    int xb = pb - yb * Wd;                    // strip: row yb, cols xb..xb+15
    int x = xb + px, y = yb;
    int tbase = wv * 3;

    const char* pkb = (const char*)packed + (size_t)b * HW * (C3 * 2);
    const char* hb = (const char*)halo;

    // ---------------- stage halo (coalesced: 5 contiguous 8.4KB row-spans) --
    for (int i = tid; i < NPR * 24; i += 192) {
        int pr = i / 24;
        int ck = i - pr * 24;
        int iy = pr / HC, ix = pr - iy * HC;
        int gy = min(max(yb - 2 + iy, 0), Hd - 1);
        int gx = min(max(xb - 3 + ix, 0), Wd - 1);
        halo[pr * (HPITCH / 16) + ck] =
            *(const f4v*)(pkb + ((size_t)(gy * Wd + gx)) * (C3 * 2) + ck * 16);
    }
    __syncthreads();

    // ---------------- Phase A: offset conv (pure-LDS B-operand) ------------
    {
        const s8v* Ap = (const s8v*)wtb2;
        f4v acc0 = {0.f, 0.f, 0.f, 0.f};
        f4v acc1 = {0.f, 0.f, 0.f, 0.f};
#pragma unroll
        for (int tt = 0; tt < 3; ++tt) {
            int t = tbase + tt;
            int ty = t / 3, tx = t - ty * 3;
            int yy = y - 1 + ty, xx = x - 1 + tx;
            bool val = (unsigned)yy < (unsigned)Hd && (unsigned)xx < (unsigned)Wd;
            short m = val ? (short)-1 : (short)0;
            int lofs = ((1 + ty) * HC + (px + 2 + tx)) * HPITCH + lg * 16;
#pragma unroll
            for (int kc = 0; kc < 2; ++kc) {
                s8v bfrag = *(const s8v*)(hb + lofs + kc * 64) & m;
                s8v a0 = Ap[((t * 2 + kc) * 2 + 0) * 64 + L];
                s8v a1 = Ap[((t * 2 + kc) * 2 + 1) * 64 + L];
                acc0 = __builtin_amdgcn_mfma_f32_16x16x32_bf16(a0, bfrag, acc0, 0, 0, 0);
                acc1 = __builtin_amdgcn_mfma_f32_16x16x32_bf16(a1, bfrag, acc1, 0, 0, 0);
            }
        }
        if (wv != 0) {
            float* r = red[wv - 1] + L * 9;
#pragma unroll
            for (int i = 0; i < 4; ++i) r[i] = acc0[i];
#pragma unroll
            for (int i = 0; i < 4; ++i) r[4 + i] = acc1[i];
        }
        __syncthreads();
        if (wv == 0) {
            const float* r0 = red[0] + L * 9;
            const float* r1 = red[1] + L * 9;
#pragma unroll
            for (int r = 0; r < 4; ++r) {
                int v = lg * 4 + r;
                off_lds[px][v] = acc0[r] + r0[r] + r1[r] + ob[v];
            }
            if (lg == 0) {
#pragma unroll
                for (int r = 0; r < 2; ++r)
                    off_lds[px][16 + r] = acc1[r] + r0[4 + r] + r1[4 + r] + ob[16 + r];
            }
        }
        __syncthreads();
    }

    // ---------------- Phase B: deform conv ----------------
    const s8v* Ap = (const s8v*)wtb;

    Ctx ctx[3];
    int ok = 1;
#pragma unroll
    for (int tt = 0; tt < 3; ++tt) {
        int t = tbase + tt;
        float2 o2 = {off_lds[px][2 * t], off_lds[px][2 * t + 1]};
        ctx[tt] = mkctx(t, y, x, xb, o2);
        ok &= ctx[tt].inh;
    }

    f4v acc[4];
    acc[0] = acc[1] = acc[2] = acc[3] = (f4v){0.f, 0.f, 0.f, 0.f};

    if (__all(ok)) {
        // fast path: bilinear gathers from LDS halo
#pragma unroll
        for (int h = 0; h < 6; ++h) {             // 3 taps x 2 halves
            int tt = h >> 1;
            int t = tbase + tt;
            int kb = (h & 1) * 3;
            const Ctx cc = ctx[tt];
            s8v rw[12];
#pragma unroll
            for (int i = 0; i < 3; ++i) {
                int co = ((kb + i) * 4 + lg) * 16;
                rw[0 * 3 + i] = *(const s8v*)(hb + cc.l00 + co);
                rw[1 * 3 + i] = *(const s8v*)(hb + cc.l01 + co);
                rw[2 * 3 + i] = *(const s8v*)(hb + cc.l10 + co);
                rw[3 * 3 + i] = *(const s8v*)(hb + cc.l11 + co);
            }
            bilin_mfma(rw, cc, Ap, t, kb, L, acc);
        }
    } else {
        // fallback: global gathers (rare; arbitrary offsets stay correct)
#pragma unroll
        for (int h = 0; h < 6; ++h) {
            int tt = h >> 1;
            int t = tbase + tt;
            int kb = (h & 1) * 3;
            const Ctx cc = ctx[tt];
            s8v rw[12];
#pragma unroll
            for (int i = 0; i < 3; ++i) {
                int co = ((kb + i) * 4 + lg) * 16;
                rw[0 * 3 + i] = *(const s8v*)(pkb + cc.o00 + co);
                rw[1 * 3 + i] = *(const s8v*)(pkb + cc.o01 + co);
                rw[2 * 3 + i] = *(const s8v*)(pkb + cc.o10 + co);
                rw[3 * 3 + i] = *(const s8v*)(pkb + cc.o11 + co);
            }
            bilin_mfma(rw, cc, Ap, t, kb, L, acc);
        }
    }

    // LDS reduction: waves 1,2 deposit 16 partials/lane; wave 0 sums+stores.
    if (wv != 0) {
        float* r = red[wv - 1] + L * 17;
#pragma unroll
        for (int mt = 0; mt < 4; ++mt)
#pragma unroll
            for (int q = 0; q < 4; ++q)
                r[mt * 4 + q] = acc[mt][q];
    }
    __syncthreads();
    if (wv == 0) {
        const float* r0 = red[0] + L * 17;
        const float* r1 = red[1] + L * 17;
#pragma unroll
        for (int mt = 0; mt < 4; ++mt) {
#pragma unroll
            for (int q = 0; q < 4; ++q) {
                int o = mt * 16 + lg * 4 + q;
                float v = acc[mt][q] + r0[mt * 4 + q] + r1[mt * 4 + q] + db[o];
                out[((size_t)(b * On + o)) * HW + pb + px] = fmaxf(v, 0.f);
            }
        }
    }
}

// ---------------------------------------------------------------------------
extern "C" void kernel_launch(void* const* d_in, const int* in_sizes, int n_in,
                              void* d_out, int out_size, void* d_ws, size_t ws_size,
                              hipStream_t stream) {
    const float* ref  = (const float*)d_in[0];
    const float* dist = (const float*)d_in[1];
    const float* ow   = (const float*)d_in[2];
    const float* ob   = (const float*)d_in[3];
    const float* dw   = (const float*)d_in[4];
    const float* db   = (const float*)d_in[5];

    float* out = (float*)d_out;               // [feat | diff], each NFEAT f32

    // ws: wtb bf16 | wtb2 bf16 | packed bf16 [NPIX][192]
    bf16* ws_wtb  = (bf16*)d_ws;
    bf16* ws_wtb2 = ws_wtb + NWTB;
    bf16* ws_pk   = ws_wtb2 + NWTB2;

    int wts_blocks = (NWTB + NWTB2 + 127) / 128;      // 1008
    repack_wts_kernel<<<NRB2 + wts_blocks, 128, 0, stream>>>(
        ref, dist, (unsigned int*)ws_pk, out + NFEAT, dw, ow, ws_wtb, ws_wtb2);
    fused_mfma<<<NPIX / 16, 192, 0, stream>>>(
        ws_pk, ws_wtb2, ob, ws_wtb, db, out);
}